// Round 10
// baseline (3417.658 us; speedup 1.0000x reference)
//
#include <hip/hip_runtime.h>

#define N_NODES 25000
#define E_EDGES 400000
#define G_GRAPHS 128

typedef short bf16x8 __attribute__((ext_vector_type(8)));
typedef float f32x4 __attribute__((ext_vector_type(4)));

__device__ __forceinline__ float b2f(unsigned short u) {
    union { unsigned int i; float f; } v; v.i = ((unsigned int)u) << 16; return v.f;
}
__device__ __forceinline__ unsigned short f2b(float f) {
    union { float f; unsigned int i; } v; v.f = f;
    unsigned int i = v.i;
    unsigned int r = i + 0x7FFFu + ((i >> 16) & 1u);
    return (unsigned short)(r >> 16);
}
__device__ __forceinline__ float ldin(const void* p, long i, int f) {
    return f ? ((const float*)p)[i] : b2f(((const unsigned short*)p)[i]);
}
// stage 8 fp16 -> bf16 LDS, with optional per-channel affine (BN fold)
__device__ __forceinline__ void stage8n(unsigned short* dl, const _Float16* sp,
                                        const float* sS, const float* sH) {
    bf16x8 r;
#pragma unroll
    for (int i = 0; i < 8; i++) r[i] = (short)f2b((float)sp[i] * sS[i] + sH[i]);
    *(bf16x8*)dl = r;
}
__device__ __forceinline__ void stage8(unsigned short* dl, const _Float16* sp) {
    bf16x8 r;
#pragma unroll
    for (int i = 0; i < 8; i++) r[i] = (short)f2b((float)sp[i]);
    *(bf16x8*)dl = r;
}
// stage 8 fp16 -> split hi/lo bf16 LDS (hi+lo == value exactly)
__device__ __forceinline__ void stage8_split(unsigned short* dh, unsigned short* dl, const _Float16* sp) {
    bf16x8 rh, rl;
#pragma unroll
    for (int i = 0; i < 8; i++) {
        float v = (float)sp[i];
        unsigned short hi = f2b(v);
        rh[i] = (short)hi;
        rl[i] = (short)f2b(v - b2f(hi));
    }
    *(bf16x8*)dh = rh;
    *(bf16x8*)dl = rl;
}

// ---------------------------------------------------------------- dtype detect
__global__ void detect_dtype(const unsigned int* __restrict__ x, int* __restrict__ flag) {
    __shared__ int cnt;
    if (threadIdx.x == 0) cnt = 0;
    __syncthreads();
    int bad = 0;
    for (int i = threadIdx.x; i < 4096; i += 256) {
        unsigned short lo = (unsigned short)(x[i] & 0xFFFFu);
        int e = (lo >> 7) & 0xFF;
        if (e != 0 && (e < 0x60 || e > 0x9F)) bad++;
    }
    atomicAdd(&cnt, bad);
    __syncthreads();
    if (threadIdx.x == 0) flag[0] = (cnt > 100) ? 1 : 0;
}

// ---------------------------------------------------------------- weights transpose -> bf16 hi + lo
__global__ void transpose_weights(const void* __restrict__ Wqkv, const void* __restrict__ WEl,
                                  const void* __restrict__ WOl, const void* __restrict__ WOel,
                                  const void* __restrict__ fW1, const void* __restrict__ fW2,
                                  const void* __restrict__ feW1, const void* __restrict__ feW2,
                                  unsigned short* __restrict__ wT,
                                  unsigned short* __restrict__ wTlo,
                                  const int* __restrict__ flag) {
    int f = flag[0];
    int m = blockIdx.x >> 6, part = blockIdx.x & 63;
    int l = m / 10, j = m % 10;
    const void* base; long eoff;
    switch (j) {
        case 0: case 1: case 2: base = Wqkv; eoff = (long)(l * 3 + j) * 16384; break;
        case 3: base = WEl;  eoff = (long)l * 16384; break;
        case 4: base = WOl;  eoff = (long)l * 16384; break;
        case 5: base = WOel; eoff = (long)l * 16384; break;
        case 6: base = fW1;  eoff = (long)l * 16384; break;
        case 7: base = fW2;  eoff = (long)l * 16384; break;
        case 8: base = feW1; eoff = (long)l * 16384; break;
        default: base = feW2; eoff = (long)l * 16384; break;
    }
    int o = part * 256 + threadIdx.x;   // o = n*128 + k
    int n = o >> 7, k = o & 127;
    float w = ldin(base, eoff + k * 128 + n, f);
    unsigned short hi = f2b(w);
    wT[(size_t)m * 16384 + o] = hi;
    wTlo[(size_t)m * 16384 + o] = f2b(w - b2f(hi));
}

// ---------------------------------------------------------------- CSR build
__global__ void zero_int(int* __restrict__ p, int n) {
    int i = blockIdx.x * 256 + threadIdx.x;
    if (i < n) p[i] = 0;
}
__global__ void zero_f32(float* __restrict__ p, int n) {
    int i = blockIdx.x * 256 + threadIdx.x;
    if (i < n) p[i] = 0.f;
}
__global__ void hist_kernel(const int* __restrict__ dst, int* __restrict__ deg, int E) {
    int i = blockIdx.x * 256 + threadIdx.x;
    if (i < E) atomicAdd(&deg[dst[i]], 1);
}
__global__ __launch_bounds__(1024) void scan_kernel(int* __restrict__ deg,
                                                    int* __restrict__ indptr, int N, int E) {
    __shared__ int tmp[1024];
    int t = threadIdx.x;
    int CH = (N + 1023) / 1024;
    int i0 = t * CH;
    int s = 0;
    for (int j = 0; j < CH; j++) { int idx = i0 + j; if (idx < N) s += deg[idx]; }
    tmp[t] = s; __syncthreads();
    for (int off = 1; off < 1024; off <<= 1) {
        int v = (t >= off) ? tmp[t - off] : 0;
        __syncthreads();
        tmp[t] += v;
        __syncthreads();
    }
    int run = (t == 0) ? 0 : tmp[t - 1];
    for (int j = 0; j < CH; j++) {
        int idx = i0 + j;
        if (idx < N) { int dv = deg[idx]; indptr[idx] = run; deg[idx] = run; run += dv; }
    }
    if (t == 0) indptr[N] = E;
}
__global__ void fill_kernel(const int* __restrict__ src, const int* __restrict__ dst,
                            int* __restrict__ cursor, int* __restrict__ pos,
                            unsigned short* __restrict__ srcCSR, int E) {
    int i = blockIdx.x * 256 + threadIdx.x;
    if (i < E) {
        int p = atomicAdd(&cursor[dst[i]], 1);
        pos[i] = p;
        srcCSR[p] = (unsigned short)src[i];
    }
}

// ---------------------------------------------------------------- init h (fp16) / e (fp16)
__global__ __launch_bounds__(256) void init_h(const void* __restrict__ x, const void* __restrict__ pe,
                                              const void* __restrict__ Wn, const void* __restrict__ Wpe,
                                              _Float16* __restrict__ h, const int* __restrict__ flag, int N) {
    __shared__ float WnS[64 * 128];
    __shared__ float WpeS[16 * 128];
    __shared__ float xr[2][64];
    __shared__ float per[2][16];
    int f = flag[0]; int t = threadIdx.x;
    for (int i = t; i < 8192; i += 256) WnS[i] = ldin(Wn, i, f);
    for (int i = t; i < 2048; i += 256) WpeS[i] = ldin(Wpe, i, f);
    long r0 = (long)blockIdx.x * 2;
    if (t < 128) { int rr = t >> 6, k = t & 63; long rg = r0 + rr; if (rg < N) xr[rr][k] = ldin(x, rg * 64 + k, f); }
    else if (t < 160) { int q = t - 128; int rr = q >> 4, k = q & 15; long rg = r0 + rr; if (rg < N) per[rr][k] = ldin(pe, rg * 16 + k, f); }
    __syncthreads();
    int half = t >> 7, c = t & 127;
    long r = r0 + half;
    if (r >= N) return;
    float acc = 0.f;
#pragma unroll 8
    for (int k = 0; k < 64; k++) acc += xr[half][k] * WnS[k * 128 + c];
#pragma unroll
    for (int k = 0; k < 16; k++) acc += per[half][k] * WpeS[k * 128 + c];
    h[r * 128 + c] = (_Float16)acc;
}
__global__ __launch_bounds__(256) void init_e(const void* __restrict__ ea, const void* __restrict__ We,
                                              _Float16* __restrict__ e, const int* __restrict__ flag, int E) {
    __shared__ float WeT[128 * 17];
    __shared__ float rows[16][16];
    int f = flag[0]; int t = threadIdx.x;
    for (int i = t; i < 2048; i += 256) {
        int k = i >> 7, c = i & 127;
        WeT[c * 17 + k] = ldin(We, i, f);
    }
    long r0 = (long)blockIdx.x * 16;
    { int rr = t >> 4, k = t & 15; rows[rr][k] = ldin(ea, (r0 + rr) * 16 + k, f); }
    __syncthreads();
#pragma unroll
    for (int p = 0; p < 8; p++) {
        int idx = t + p * 256;
        int rr = idx >> 7, c = idx & 127;
        float acc = 0.f;
#pragma unroll
        for (int k = 0; k < 16; k++) acc += rows[rr][k] * WeT[c * 17 + k];
        e[(r0 + rr) * 128 + c] = (_Float16)acc;
    }
}

// ---------------------------------------------------------------- node GEMM (split precision)
template <bool RELU, bool RES>
__global__ __launch_bounds__(256, 2) void gemm_node(const _Float16* __restrict__ A,
                                                    const unsigned short* __restrict__ Wt,
                                                    const unsigned short* __restrict__ Wtlo,
                                                    const void* __restrict__ bias, long boff,
                                                    const _Float16* __restrict__ Rp,
                                                    _Float16* __restrict__ C, int M,
                                                    const int* __restrict__ flag) {
    __shared__ unsigned short Ah[128 * 136];
    __shared__ unsigned short Al[128 * 136];
    int t = threadIdx.x;
    long bRow = (long)blockIdx.x * 128;
    {
        int r = t >> 1, ch = (t & 1) * 64;
        long gr = bRow + r;
        unsigned short* dh = &Ah[r * 136 + ch];
        unsigned short* dl = &Al[r * 136 + ch];
        if (gr < M) {
            const _Float16* sp = A + gr * 128 + ch;
#pragma unroll
            for (int i = 0; i < 8; i++) stage8_split(dh + i * 8, dl + i * 8, sp + i * 8);
        } else {
            int4 z = make_int4(0, 0, 0, 0);
#pragma unroll
            for (int i = 0; i < 8; i++) { *(int4*)(dh + i * 8) = z; *(int4*)(dl + i * 8) = z; }
        }
    }
    __syncthreads();
    int wave = t >> 6, lane = t & 63;
    int wr = (wave >> 1) * 64, wc = (wave & 1) * 64;
    int lm = lane & 15, lq = lane >> 4;
    f32x4 acc[4][4];
#pragma unroll
    for (int i = 0; i < 4; i++)
#pragma unroll
        for (int j = 0; j < 4; j++) acc[i][j] = (f32x4){0.f, 0.f, 0.f, 0.f};
#pragma unroll
    for (int ks = 0; ks < 4; ks++) {
        int ko = ks * 32 + lq * 8;
        bf16x8 bh[4], bl[4], ah[4], al[4];
#pragma unroll
        for (int j = 0; j < 4; j++) {
            bh[j] = *(const bf16x8*)(Wt + (wc + j * 16 + lm) * 128 + ko);
            bl[j] = *(const bf16x8*)(Wtlo + (wc + j * 16 + lm) * 128 + ko);
        }
#pragma unroll
        for (int i = 0; i < 4; i++) {
            ah[i] = *(const bf16x8*)&Ah[(wr + i * 16 + lm) * 136 + ko];
            al[i] = *(const bf16x8*)&Al[(wr + i * 16 + lm) * 136 + ko];
        }
#pragma unroll
        for (int i = 0; i < 4; i++)
#pragma unroll
            for (int j = 0; j < 4; j++) {
                acc[i][j] = __builtin_amdgcn_mfma_f32_16x16x32_bf16(ah[i], bh[j], acc[i][j], 0, 0, 0);
                acc[i][j] = __builtin_amdgcn_mfma_f32_16x16x32_bf16(al[i], bh[j], acc[i][j], 0, 0, 0);
                acc[i][j] = __builtin_amdgcn_mfma_f32_16x16x32_bf16(ah[i], bl[j], acc[i][j], 0, 0, 0);
            }
    }
    int f = flag[0];
#pragma unroll
    for (int j = 0; j < 4; j++) {
        int col = wc + j * 16 + lm;
        float bv = ldin(bias, boff + col, f);
#pragma unroll
        for (int i = 0; i < 4; i++) {
#pragma unroll
            for (int r4 = 0; r4 < 4; r4++) {
                long grow = bRow + wr + i * 16 + lq * 4 + r4;
                if (grow < M) {
                    float v = acc[i][j][r4] + bv;
                    if (RES) v += (float)Rp[grow * 128 + col];
                    if (RELU) v = v > 0.f ? v : 0.f;
                    C[grow * 128 + col] = (_Float16)v;
                }
            }
        }
    }
}

// ---------------------------------------------------------------- Q,K GEMMs (h staged once, split precision)
__global__ __launch_bounds__(256, 2) void node_qk(const _Float16* __restrict__ h,
                                                  const unsigned short* __restrict__ wq,
                                                  const unsigned short* __restrict__ wqlo,
                                                  const unsigned short* __restrict__ wk,
                                                  const unsigned short* __restrict__ wklo,
                                                  const void* __restrict__ bqkv, long boff0,
                                                  _Float16* __restrict__ Qb,
                                                  _Float16* __restrict__ Kb,
                                                  const int* __restrict__ flag, int M) {
    __shared__ unsigned short Ah[128 * 136];
    __shared__ unsigned short Al[128 * 136];
    int t = threadIdx.x;
    long bRow = (long)blockIdx.x * 128;
    {
        int r = t >> 1, ch = (t & 1) * 64;
        long gr = bRow + r;
        unsigned short* dh = &Ah[r * 136 + ch];
        unsigned short* dl = &Al[r * 136 + ch];
        if (gr < M) {
            const _Float16* sp = h + gr * 128 + ch;
#pragma unroll
            for (int i = 0; i < 8; i++) stage8_split(dh + i * 8, dl + i * 8, sp + i * 8);
        } else {
            int4 z = make_int4(0, 0, 0, 0);
#pragma unroll
            for (int i = 0; i < 8; i++) { *(int4*)(dh + i * 8) = z; *(int4*)(dl + i * 8) = z; }
        }
    }
    __syncthreads();
    int wave = t >> 6, lane = t & 63;
    int wr = (wave >> 1) * 64, wc = (wave & 1) * 64;
    int lm = lane & 15, lq = lane >> 4;
    int f = flag[0];
    _Float16* outs[2] = {Qb, Kb};
    const unsigned short* whi[2] = {wq, wk};
    const unsigned short* wlo[2] = {wqlo, wklo};
    for (int w = 0; w < 2; w++) {
        f32x4 acc[4][4];
#pragma unroll
        for (int i = 0; i < 4; i++)
#pragma unroll
            for (int j = 0; j < 4; j++) acc[i][j] = (f32x4){0.f, 0.f, 0.f, 0.f};
#pragma unroll
        for (int ks = 0; ks < 4; ks++) {
            int ko = ks * 32 + lq * 8;
            bf16x8 bh[4], bl[4], ah[4], al[4];
#pragma unroll
            for (int j = 0; j < 4; j++) {
                bh[j] = *(const bf16x8*)(whi[w] + (wc + j * 16 + lm) * 128 + ko);
                bl[j] = *(const bf16x8*)(wlo[w] + (wc + j * 16 + lm) * 128 + ko);
            }
#pragma unroll
            for (int i = 0; i < 4; i++) {
                ah[i] = *(const bf16x8*)&Ah[(wr + i * 16 + lm) * 136 + ko];
                al[i] = *(const bf16x8*)&Al[(wr + i * 16 + lm) * 136 + ko];
            }
#pragma unroll
            for (int i = 0; i < 4; i++)
#pragma unroll
                for (int j = 0; j < 4; j++) {
                    acc[i][j] = __builtin_amdgcn_mfma_f32_16x16x32_bf16(ah[i], bh[j], acc[i][j], 0, 0, 0);
                    acc[i][j] = __builtin_amdgcn_mfma_f32_16x16x32_bf16(al[i], bh[j], acc[i][j], 0, 0, 0);
                    acc[i][j] = __builtin_amdgcn_mfma_f32_16x16x32_bf16(ah[i], bl[j], acc[i][j], 0, 0, 0);
                }
        }
        _Float16* O = outs[w];
#pragma unroll
        for (int j = 0; j < 4; j++) {
            int col = wc + j * 16 + lm;
            float bv = ldin(bqkv, boff0 + w * 128 + col, f);
#pragma unroll
            for (int i = 0; i < 4; i++)
#pragma unroll
                for (int r4 = 0; r4 < 4; r4++) {
                    long grow = bRow + wr + i * 16 + lq * 4 + r4;
                    if (grow < M) O[grow * 128 + col] = (_Float16)(acc[i][j][r4] + bv);
                }
        }
    }
}

// ---------------------------------------------------------------- fused edge attention (BN-folded input)
// input e_norm = ebuf*nS+nH (nS null -> identity); writeE=0: scores only (layer 3)
template <typename TS>
__global__ __launch_bounds__(256, 4) void edge_fused0(_Float16* __restrict__ ebuf,
                                                      const unsigned short* __restrict__ W1t,
                                                      const unsigned short* __restrict__ W2t,
                                                      const void* __restrict__ bias1, long b1off,
                                                      const void* __restrict__ bias2, long b2off,
                                                      const _Float16* __restrict__ Qb,
                                                      const _Float16* __restrict__ Kb,
                                                      const int* __restrict__ srcp,
                                                      const int* __restrict__ dstp,
                                                      const int* __restrict__ posp,
                                                      TS* __restrict__ score,
                                                      const int* __restrict__ flag,
                                                      const float* __restrict__ nS,
                                                      const float* __restrict__ nH,
                                                      int writeE) {
    __shared__ unsigned short Es[128 * 136];
    __shared__ int sdst[128], ssrc[128], spos[128];
    __shared__ float nSs[128], nHs[128];
    int t = threadIdx.x;
    long bRow = (long)blockIdx.x * 128;   // E % 128 == 0
    if (t < 128) {
        nSs[t] = nS ? nS[t] : 1.f;
        nHs[t] = nH ? nH[t] : 0.f;
        sdst[t] = dstp[bRow + t]; ssrc[t] = srcp[bRow + t]; spos[t] = posp[bRow + t];
    }
    __syncthreads();
    {
        int r = t >> 1, ch = (t & 1) * 64;
        const _Float16* sp = ebuf + (bRow + r) * 128 + ch;
        unsigned short* dl = &Es[r * 136 + ch];
#pragma unroll
        for (int i = 0; i < 8; i++) stage8n(dl + i * 8, sp + i * 8, &nSs[ch + i * 8], &nHs[ch + i * 8]);
    }
    __syncthreads();
    int wave = t >> 6, lane = t & 63;
    int wr = (wave >> 1) * 64, wc = (wave & 1) * 64;
    int lm = lane & 15, lq = lane >> 4;
    int f = flag[0];
    // ---- GEMM1: Eh
    f32x4 acc[4][4];
#pragma unroll
    for (int i = 0; i < 4; i++)
#pragma unroll
        for (int j = 0; j < 4; j++) acc[i][j] = (f32x4){0.f, 0.f, 0.f, 0.f};
    {
        bf16x8 bfr[4][4];
#pragma unroll
        for (int ks = 0; ks < 4; ks++)
#pragma unroll
            for (int j = 0; j < 4; j++)
                bfr[ks][j] = *(const bf16x8*)(W1t + (wc + j * 16 + lm) * 128 + ks * 32 + lq * 8);
#pragma unroll
        for (int ks = 0; ks < 4; ks++) {
            int ko = ks * 32 + lq * 8;
            bf16x8 af[4];
#pragma unroll
            for (int i = 0; i < 4; i++) af[i] = *(const bf16x8*)&Es[(wr + i * 16 + lm) * 136 + ko];
#pragma unroll
            for (int i = 0; i < 4; i++)
#pragma unroll
                for (int j = 0; j < 4; j++)
                    acc[i][j] = __builtin_amdgcn_mfma_f32_16x16x32_bf16(af[i], bfr[ks][j], acc[i][j], 0, 0, 0);
        }
    }
    __syncthreads();   // all waves done reading Es (GEMM1)
    // ---- middle: qijk = (Eh+b1) * Q[dst] * K[src] * SCALE
#pragma unroll
    for (int j = 0; j < 4; j++) {
        int col = wc + j * 16 + lm;
        float bv = ldin(bias1, b1off + col, f);
#pragma unroll
        for (int i = 0; i < 4; i++) {
#pragma unroll
            for (int r4 = 0; r4 < 4; r4++) {
                int rl = wr + i * 16 + lq * 4 + r4;
                float eh = acc[i][j][r4] + bv;
                float qv = (float)Qb[(long)sdst[rl] * 128 + col];
                float kv = (float)Kb[(long)ssrc[rl] * 128 + col];
                acc[i][j][r4] = eh * qv * kv * 0.25f;
            }
        }
    }
    // ---- score: reduce 16-col head segments; scatter to CSR slot
#pragma unroll
    for (int i = 0; i < 4; i++)
#pragma unroll
        for (int j = 0; j < 4; j++)
#pragma unroll
            for (int r4 = 0; r4 < 4; r4++) {
                float s = acc[i][j][r4];
                s += __shfl_xor(s, 1); s += __shfl_xor(s, 2);
                s += __shfl_xor(s, 4); s += __shfl_xor(s, 8);
                if (lm == 0) {
                    int rl = wr + i * 16 + lq * 4 + r4;
                    s = fminf(fmaxf(s, -60000.f), 60000.f);
                    score[(long)spos[rl] * 8 + (wc >> 4) + j] = (TS)s;
                }
            }
    if (!writeE) return;   // layer 3: edge state dead downstream
    // ---- write qijk to Es as A-operand of GEMM2
#pragma unroll
    for (int i = 0; i < 4; i++)
#pragma unroll
        for (int j = 0; j < 4; j++)
#pragma unroll
            for (int r4 = 0; r4 < 4; r4++)
                Es[(wr + i * 16 + lq * 4 + r4) * 136 + wc + j * 16 + lm] = f2b(acc[i][j][r4]);
    __syncthreads();
    // ---- GEMM2: qijk @ WOel + bOel + e_norm  (raw store)
#pragma unroll
    for (int i = 0; i < 4; i++)
#pragma unroll
        for (int j = 0; j < 4; j++) acc[i][j] = (f32x4){0.f, 0.f, 0.f, 0.f};
    {
        bf16x8 bfr[4][4];
#pragma unroll
        for (int ks = 0; ks < 4; ks++)
#pragma unroll
            for (int j = 0; j < 4; j++)
                bfr[ks][j] = *(const bf16x8*)(W2t + (wc + j * 16 + lm) * 128 + ks * 32 + lq * 8);
#pragma unroll
        for (int ks = 0; ks < 4; ks++) {
            int ko = ks * 32 + lq * 8;
            bf16x8 af[4];
#pragma unroll
            for (int i = 0; i < 4; i++) af[i] = *(const bf16x8*)&Es[(wr + i * 16 + lm) * 136 + ko];
#pragma unroll
            for (int i = 0; i < 4; i++)
#pragma unroll
                for (int j = 0; j < 4; j++)
                    acc[i][j] = __builtin_amdgcn_mfma_f32_16x16x32_bf16(af[i], bfr[ks][j], acc[i][j], 0, 0, 0);
        }
    }
#pragma unroll
    for (int j = 0; j < 4; j++) {
        int col = wc + j * 16 + lm;
        float bo = ldin(bias2, b2off + col, f);
        float sc = nSs[col], sh = nHs[col];
#pragma unroll
        for (int i = 0; i < 4; i++)
#pragma unroll
            for (int r4 = 0; r4 < 4; r4++) {
                long ge = bRow + wr + i * 16 + lq * 4 + r4;
                float en = (float)ebuf[ge * 128 + col] * sc + sh;
                ebuf[ge * 128 + col] = (_Float16)(acc[i][j][r4] + bo + en);
            }
    }
}

// ---------------------------------------------------------------- edge FFN (BN-folded input, in-place)
__global__ __launch_bounds__(256, 4) void edge_ffn(_Float16* __restrict__ ebuf,
                                                   const unsigned short* __restrict__ W1t,
                                                   const unsigned short* __restrict__ W2t,
                                                   const void* __restrict__ bias1, long b1off,
                                                   const void* __restrict__ bias2, long b2off,
                                                   const int* __restrict__ flag,
                                                   const float* __restrict__ nS,
                                                   const float* __restrict__ nH) {
    __shared__ unsigned short Es[128 * 136];
    __shared__ float nSs[128], nHs[128];
    int t = threadIdx.x;
    long bRow = (long)blockIdx.x * 128;
    if (t < 128) { nSs[t] = nS[t]; nHs[t] = nH[t]; }
    __syncthreads();
    {
        int r = t >> 1, ch = (t & 1) * 64;
        const _Float16* sp = ebuf + (bRow + r) * 128 + ch;
        unsigned short* dl = &Es[r * 136 + ch];
#pragma unroll
        for (int i = 0; i < 8; i++) stage8n(dl + i * 8, sp + i * 8, &nSs[ch + i * 8], &nHs[ch + i * 8]);
    }
    __syncthreads();
    int wave = t >> 6, lane = t & 63;
    int wr = (wave >> 1) * 64, wc = (wave & 1) * 64;
    int lm = lane & 15, lq = lane >> 4;
    int f = flag[0];
    f32x4 acc[4][4];
#pragma unroll
    for (int i = 0; i < 4; i++)
#pragma unroll
        for (int j = 0; j < 4; j++) acc[i][j] = (f32x4){0.f, 0.f, 0.f, 0.f};
#pragma unroll
    for (int ks = 0; ks < 4; ks++) {
        int ko = ks * 32 + lq * 8;
        bf16x8 bfr[4], af[4];
#pragma unroll
        for (int j = 0; j < 4; j++) bfr[j] = *(const bf16x8*)(W1t + (wc + j * 16 + lm) * 128 + ko);
#pragma unroll
        for (int i = 0; i < 4; i++) af[i] = *(const bf16x8*)&Es[(wr + i * 16 + lm) * 136 + ko];
#pragma unroll
        for (int i = 0; i < 4; i++)
#pragma unroll
            for (int j = 0; j < 4; j++)
                acc[i][j] = __builtin_amdgcn_mfma_f32_16x16x32_bf16(af[i], bfr[j], acc[i][j], 0, 0, 0);
    }
    __syncthreads();
#pragma unroll
    for (int j = 0; j < 4; j++) {
        int col = wc + j * 16 + lm;
        float bv = ldin(bias1, b1off + col, f);
#pragma unroll
        for (int i = 0; i < 4; i++)
#pragma unroll
            for (int r4 = 0; r4 < 4; r4++) {
                float v = acc[i][j][r4] + bv;
                v = v > 0.f ? v : 0.f;
                Es[(wr + i * 16 + lq * 4 + r4) * 136 + col] = f2b(v);
            }
    }
    __syncthreads();
#pragma unroll
    for (int i = 0; i < 4; i++)
#pragma unroll
        for (int j = 0; j < 4; j++) acc[i][j] = (f32x4){0.f, 0.f, 0.f, 0.f};
#pragma unroll
    for (int ks = 0; ks < 4; ks++) {
        int ko = ks * 32 + lq * 8;
        bf16x8 bfr[4], af[4];
#pragma unroll
        for (int j = 0; j < 4; j++) bfr[j] = *(const bf16x8*)(W2t + (wc + j * 16 + lm) * 128 + ko);
#pragma unroll
        for (int i = 0; i < 4; i++) af[i] = *(const bf16x8*)&Es[(wr + i * 16 + lm) * 136 + ko];
#pragma unroll
        for (int i = 0; i < 4; i++)
#pragma unroll
            for (int j = 0; j < 4; j++)
                acc[i][j] = __builtin_amdgcn_mfma_f32_16x16x32_bf16(af[i], bfr[j], acc[i][j], 0, 0, 0);
    }
#pragma unroll
    for (int j = 0; j < 4; j++) {
        int col = wc + j * 16 + lm;
        float bv = ldin(bias2, b2off + col, f);
        float sc = nSs[col], sh = nHs[col];
#pragma unroll
        for (int i = 0; i < 4; i++)
#pragma unroll
            for (int r4 = 0; r4 < 4; r4++) {
                long ge = bRow + wr + i * 16 + lq * 4 + r4;
                float en = (float)ebuf[ge * 128 + col] * sc + sh;
                ebuf[ge * 128 + col] = (_Float16)(acc[i][j][r4] + bv + en);
            }
    }
}

// ---------------------------------------------------------------- softmax+agg (CSR-contiguous)
template <typename TS>
__global__ __launch_bounds__(256) void agg_kernel(const int* __restrict__ indptr,
                                                  const unsigned short* __restrict__ srcCSR,
                                                  const TS* __restrict__ score,
                                                  const _Float16* __restrict__ V,
                                                  _Float16* __restrict__ agg, int N) {
    int wave = threadIdx.x >> 6, lane = threadIdx.x & 63;
    int n = blockIdx.x * 4 + wave;
    if (n >= N) return;
    int beg = indptr[n], end = indptr[n + 1];
    int h0 = lane >> 4, h1 = 4 + h0;
    float m0 = -3.402823466e38f, m1 = -3.402823466e38f;
    for (int i = beg; i < end; i++) {
        m0 = fmaxf(m0, (float)score[(long)i * 8 + h0]);
        m1 = fmaxf(m1, (float)score[(long)i * 8 + h1]);
    }
    float a0 = 0.f, a1 = 0.f, d0 = 0.f, d1 = 0.f;
    for (int i = beg; i < end; i++) {
        int sv = srcCSR[i];
        float p0 = __expf((float)score[(long)i * 8 + h0] - m0);
        float p1 = __expf((float)score[(long)i * 8 + h1] - m1);
        d0 += p0; d1 += p1;
        a0 += p0 * (float)V[(long)sv * 128 + lane];
        a1 += p1 * (float)V[(long)sv * 128 + 64 + lane];
    }
    float inv0 = 1.f / (d0 + 1e-16f), inv1 = 1.f / (d1 + 1e-16f);
    agg[(long)n * 128 + lane] = (_Float16)(a0 * inv0);
    agg[(long)n * 128 + 64 + lane] = (_Float16)(a1 * inv1);
}

// ---------------------------------------------------------------- BatchNorm
__global__ __launch_bounds__(256) void bn_stats(const _Float16* __restrict__ y, float* __restrict__ sums, int M) {
    __shared__ float lsum[16 * 128];
    __shared__ float lss[16 * 128];
    int t = threadIdx.x;
    int chb = (t & 15) * 8;
    int rowlane = t >> 4;
    float s[8], ss[8];
#pragma unroll
    for (int k = 0; k < 8; k++) { s[k] = 0.f; ss[k] = 0.f; }
    for (long r = (long)blockIdx.x * 16 + rowlane; r < M; r += (long)gridDim.x * 16) {
        int4 raw = *(const int4*)(y + r * 128 + chb);
        const _Float16* a = (const _Float16*)&raw;
#pragma unroll
        for (int k = 0; k < 8; k++) {
            float v = (float)a[k];
            s[k] += v; ss[k] += v * v;
        }
    }
#pragma unroll
    for (int k = 0; k < 8; k++) {
        lsum[rowlane * 128 + chb + k] = s[k];
        lss[rowlane * 128 + chb + k] = ss[k];
    }
    __syncthreads();
    if (t < 128) {
        float t1 = 0.f, t2 = 0.f;
#pragma unroll
        for (int row = 0; row < 16; row++) {
            t1 += lsum[row * 128 + t];
            t2 += lss[row * 128 + t];
        }
        atomicAdd(&sums[t], t1);
        atomicAdd(&sums[128 + t], t2);
    }
}
__global__ void bn_finalize(const float* __restrict__ sums,
                            const void* __restrict__ gamma, long goff,
                            const void* __restrict__ beta, long boff,
                            float* __restrict__ scale, float* __restrict__ shift,
                            float invM, const int* __restrict__ flag) {
    int f = flag[0];
    int c = threadIdx.x;
    float mu = sums[c] * invM;
    float var = fmaxf(sums[128 + c] * invM - mu * mu, 0.f);
    float rs = rsqrtf(var + 1e-5f);
    float g = ldin(gamma, goff + c, f) * rs;
    scale[c] = g;
    shift[c] = ldin(beta, boff + c, f) - mu * g;
}
__global__ void bn_apply(_Float16* __restrict__ y, const float* __restrict__ scale,
                         const float* __restrict__ shift, long total) {
    long idx = ((long)blockIdx.x * 256 + threadIdx.x) * 8;
    long stride = (long)gridDim.x * 256 * 8;
    for (; idx < total; idx += stride) {
        int cb = (int)(idx & 127);
        _Float16* p = y + idx;
        int4 v = *(int4*)p;
        _Float16* a = (_Float16*)&v;
        _Float16 o[8];
#pragma unroll
        for (int k = 0; k < 8; k++) o[k] = (_Float16)((float)a[k] * scale[cb + k] + shift[cb + k]);
        *(int4*)p = *(int4*)o;
    }
}

// ---------------------------------------------------------------- pool + heads
__global__ __launch_bounds__(128) void pool_kernel(const _Float16* __restrict__ h,
                                                   const int* __restrict__ batch,
                                                   float* __restrict__ g, int N) {
    int gid = blockIdx.x;
    int lo = 0, hi = N;
    while (lo < hi) { int mid = (lo + hi) >> 1; if (batch[mid] < gid) lo = mid + 1; else hi = mid; }
    int beg = lo;
    hi = N;
    while (lo < hi) { int mid = (lo + hi) >> 1; if (batch[mid] < gid + 1) lo = mid + 1; else hi = mid; }
    int end = lo;
    int c = threadIdx.x;
    float acc = 0.f;
    for (int r = beg; r < end; r++) acc += (float)h[(long)r * 128 + c];
    g[gid * 128 + c] = acc;
}
__global__ __launch_bounds__(128) void head_kernel(const float* __restrict__ g,
                                                   const void* muW1, const void* mub1,
                                                   const void* muW2, const void* mub2,
                                                   const void* lvW1, const void* lvb1,
                                                   const void* lvW2, const void* lvb2,
                                                   void* __restrict__ out, const int* __restrict__ flag) {
    __shared__ float gr[128];
    __shared__ float red[128];
    int f = flag[0];
    int r = blockIdx.x, t = threadIdx.x;
    gr[t] = g[r * 128 + t];
    __syncthreads();
    float acc = ldin(mub1, t, f);
    for (int k = 0; k < 128; k++) acc += gr[k] * ldin(muW1, k * 128 + t, f);
    acc = fmaxf(acc, 0.f);
    red[t] = acc * ldin(muW2, t, f);
    __syncthreads();
    for (int s = 64; s > 0; s >>= 1) { if (t < s) red[t] += red[t + s]; __syncthreads(); }
    if (t == 0) {
        float v = red[0] + ldin(mub2, 0, f);
        if (f) ((float*)out)[r] = v; else ((unsigned short*)out)[r] = f2b(v);
    }
    __syncthreads();
    acc = ldin(lvb1, t, f);
    for (int k = 0; k < 128; k++) acc += gr[k] * ldin(lvW1, k * 128 + t, f);
    acc = fmaxf(acc, 0.f);
    red[t] = acc * ldin(lvW2, t, f);
    __syncthreads();
    for (int s = 64; s > 0; s >>= 1) { if (t < s) red[t] += red[t + s]; __syncthreads(); }
    if (t == 0) {
        float v = __expf(0.5f * (red[0] + ldin(lvb2, 0, f)));
        if (f) ((float*)out)[128 + r] = v; else ((unsigned short*)out)[128 + r] = f2b(v);
    }
}

// ---------------------------------------------------------------- host
extern "C" void kernel_launch(void* const* d_in, const int* in_sizes, int n_in,
                              void* d_out, int out_size, void* d_ws, size_t ws_size,
                              hipStream_t stream) {
    const void* x    = d_in[0];
    const void* ea   = d_in[1];
    const void* pe   = d_in[2];
    const int* eidx  = (const int*)d_in[3];
    const int* batch = (const int*)d_in[4];
    const int* srcp = eidx;
    const int* dstp = eidx + E_EDGES;

    bool score_f32 = (ws_size >= 148000000ULL);
    size_t ts_size = score_f32 ? 4 : 2;

    char* wsb = (char*)d_ws;
    size_t off = 0;
    auto alloc = [&](size_t bytes) -> char* {
        char* p = wsb + off;
        off = (off + bytes + 255) & ~(size_t)255;
        return p;
    };
    int* dflag            = (int*)alloc(256);
    unsigned short* wT    = (unsigned short*)alloc(40UL * 16384 * 2);
    unsigned short* wTlo  = (unsigned short*)alloc(40UL * 16384 * 2);
    _Float16* ebuf        = (_Float16*)alloc((size_t)E_EDGES * 128 * 2);
    _Float16* hbuf        = (_Float16*)alloc((size_t)N_NODES * 128 * 2);
    char* slotA           = alloc((size_t)N_NODES * 128 * 2);
    char* slotB           = alloc((size_t)N_NODES * 128 * 2);
    char* scoreB          = alloc((size_t)E_EDGES * 8 * ts_size);
    int* indptr           = (int*)alloc((size_t)(N_NODES + 1) * 4);
    int* deg              = (int*)alloc((size_t)N_NODES * 4);
    int* pos              = (int*)alloc((size_t)E_EDGES * 4);
    unsigned short* srcCSR= (unsigned short*)alloc((size_t)E_EDGES * 2);
    float* sums           = (float*)alloc(256 * 4);
    float* scalArr        = (float*)alloc(16 * 128 * 4);   // per-BN-slot scale
    float* shftArr        = (float*)alloc(16 * 128 * 4);   // per-BN-slot shift
    float* gpool          = (float*)scoreB;

    _Float16* Qb = (_Float16*)slotA;
    _Float16* Kb = (_Float16*)slotB;
    _Float16* Vb = (_Float16*)slotA;
    _Float16* aggb = (_Float16*)slotB;
    _Float16* hid  = (_Float16*)slotA;

    detect_dtype<<<1, 256, 0, stream>>>((const unsigned int*)x, dflag);
    transpose_weights<<<2560, 256, 0, stream>>>(d_in[8], d_in[10], d_in[12], d_in[14],
                                                d_in[16], d_in[18], d_in[20], d_in[22], wT, wTlo, dflag);
    zero_int<<<(N_NODES + 255) / 256, 256, 0, stream>>>(deg, N_NODES);
    hist_kernel<<<(E_EDGES + 255) / 256, 256, 0, stream>>>(dstp, deg, E_EDGES);
    scan_kernel<<<1, 1024, 0, stream>>>(deg, indptr, N_NODES, E_EDGES);
    fill_kernel<<<(E_EDGES + 255) / 256, 256, 0, stream>>>(srcp, dstp, deg, pos, srcCSR, E_EDGES);
    init_h<<<(N_NODES + 1) / 2, 256, 0, stream>>>(x, pe, d_in[5], d_in[7], hbuf, dflag, N_NODES);
    init_e<<<E_EDGES / 16, 256, 0, stream>>>(ea, d_in[6], ebuf, dflag, E_EDGES);

    const int gN = (N_NODES + 127) / 128;
    const int gE = E_EDGES / 128;

    // stats+finalize into slot s (no apply)
    auto bn_sf = [&](_Float16* y, int M, int s) {
        zero_f32<<<1, 256, 0, stream>>>(sums, 256);
        int sb = (M + 15) / 16; if (sb > 1024) sb = 1024;
        bn_stats<<<sb, 256, 0, stream>>>(y, sums, M);
        bn_finalize<<<1, 128, 0, stream>>>(sums, d_in[24], (long)s * 128, d_in[25], (long)s * 128,
                                           scalArr + s * 128, shftArr + s * 128, 1.f / (float)M, dflag);
    };
    // full BN (node path): stats+finalize+apply
    auto bn_full = [&](_Float16* y, int M, int s) {
        bn_sf(y, M, s);
        long total = (long)M * 128;
        int grid = (int)((total / 8 + 255) / 256); if (grid > 4096) grid = 4096;
        bn_apply<<<grid, 256, 0, stream>>>(y, scalArr + s * 128, shftArr + s * 128, total);
    };

    for (int l = 0; l < 4; l++) {
        const unsigned short* WTl = wT + (size_t)l * 10 * 16384;
        const unsigned short* WTlol = wTlo + (size_t)l * 10 * 16384;
        int writeE = (l < 3) ? 1 : 0;
        // pending edge-BN from previous layer (slot (l-1)*4+3); l=0: identity
        const float* eS = (l > 0) ? scalArr + ((l - 1) * 4 + 3) * 128 : nullptr;
        const float* eH = (l > 0) ? shftArr + ((l - 1) * 4 + 3) * 128 : nullptr;

        node_qk<<<gN, 256, 0, stream>>>(hbuf, WTl + 0 * 16384, WTlol + 0 * 16384,
                                        WTl + 1 * 16384, WTlol + 1 * 16384,
                                        d_in[9], (long)(l * 3) * 128, Qb, Kb, dflag, N_NODES);
        if (score_f32)
            edge_fused0<float><<<gE, 256, 0, stream>>>(ebuf, WTl + 3 * 16384, WTl + 5 * 16384,
                                                       d_in[11], (long)l * 128, d_in[15], (long)l * 128,
                                                       Qb, Kb, srcp, dstp, pos, (float*)scoreB, dflag, eS, eH, writeE);
        else
            edge_fused0<_Float16><<<gE, 256, 0, stream>>>(ebuf, WTl + 3 * 16384, WTl + 5 * 16384,
                                                          d_in[11], (long)l * 128, d_in[15], (long)l * 128,
                                                          Qb, Kb, srcp, dstp, pos, (_Float16*)scoreB, dflag, eS, eH, writeE);
        gemm_node<false, false><<<gN, 256, 0, stream>>>(hbuf, WTl + 2 * 16384, WTlol + 2 * 16384,
                                                        d_in[9], (long)(l * 3 + 2) * 128, nullptr, Vb, N_NODES, dflag);
        if (score_f32)
            agg_kernel<float><<<(N_NODES + 3) / 4, 256, 0, stream>>>(indptr, srcCSR, (const float*)scoreB, Vb, aggb, N_NODES);
        else
            agg_kernel<_Float16><<<(N_NODES + 3) / 4, 256, 0, stream>>>(indptr, srcCSR, (const _Float16*)scoreB, Vb, aggb, N_NODES);
        gemm_node<false, true><<<gN, 256, 0, stream>>>(aggb, WTl + 4 * 16384, WTlol + 4 * 16384,
                                                       d_in[13], (long)l * 128, hbuf, hbuf, N_NODES, dflag);
        bn_full(hbuf, N_NODES, l * 4 + 0);
        gemm_node<true, false><<<gN, 256, 0, stream>>>(hbuf, WTl + 6 * 16384, WTlol + 6 * 16384,
                                                       d_in[17], (long)l * 128, nullptr, hid, N_NODES, dflag);
        gemm_node<false, true><<<gN, 256, 0, stream>>>(hid, WTl + 7 * 16384, WTlol + 7 * 16384,
                                                       d_in[19], (long)l * 128, hbuf, hbuf, N_NODES, dflag);
        bn_full(hbuf, N_NODES, l * 4 + 1);
        // edge branch (l<3): BN folded into consumers
        if (l < 3) {
            bn_sf(ebuf, E_EDGES, l * 4 + 2);   // stats over raw u
            edge_ffn<<<gE, 256, 0, stream>>>(ebuf, WTl + 8 * 16384, WTl + 9 * 16384,
                                             d_in[21], (long)l * 128, d_in[23], (long)l * 128, dflag,
                                             scalArr + (l * 4 + 2) * 128, shftArr + (l * 4 + 2) * 128);
            bn_sf(ebuf, E_EDGES, l * 4 + 3);   // stats over raw v (applied next layer)
        }
    }

    pool_kernel<<<G_GRAPHS, 128, 0, stream>>>(hbuf, batch, gpool, N_NODES);
    head_kernel<<<G_GRAPHS, 128, 0, stream>>>(gpool, d_in[26], d_in[27], d_in[28], d_in[29],
                                              d_in[30], d_in[31], d_in[32], d_in[33], d_out, dflag);
}

// Round 11
// 3091.086 us; speedup vs baseline: 1.1056x; 1.1056x over previous
//
#include <hip/hip_runtime.h>

#define N_NODES 25000
#define E_EDGES 400000
#define G_GRAPHS 128

typedef short bf16x8 __attribute__((ext_vector_type(8)));
typedef float f32x4 __attribute__((ext_vector_type(4)));

__device__ __forceinline__ float b2f(unsigned short u) {
    union { unsigned int i; float f; } v; v.i = ((unsigned int)u) << 16; return v.f;
}
__device__ __forceinline__ unsigned short f2b(float f) {
    union { float f; unsigned int i; } v; v.f = f;
    unsigned int i = v.i;
    unsigned int r = i + 0x7FFFu + ((i >> 16) & 1u);
    return (unsigned short)(r >> 16);
}
__device__ __forceinline__ float ldin(const void* p, long i, int f) {
    return f ? ((const float*)p)[i] : b2f(((const unsigned short*)p)[i]);
}
// stage 8 fp16 -> bf16 LDS, with per-channel affine (BN fold)
__device__ __forceinline__ void stage8n(unsigned short* dl, const _Float16* sp,
                                        const float* sS, const float* sH) {
    bf16x8 r;
#pragma unroll
    for (int i = 0; i < 8; i++) r[i] = (short)f2b((float)sp[i] * sS[i] + sH[i]);
    *(bf16x8*)dl = r;
}
__device__ __forceinline__ void stage8(unsigned short* dl, const _Float16* sp) {
    bf16x8 r;
#pragma unroll
    for (int i = 0; i < 8; i++) r[i] = (short)f2b((float)sp[i]);
    *(bf16x8*)dl = r;
}
// stage 8 fp16 -> split hi/lo bf16 LDS (hi+lo == value exactly)
__device__ __forceinline__ void stage8_split(unsigned short* dh, unsigned short* dl, const _Float16* sp) {
    bf16x8 rh, rl;
#pragma unroll
    for (int i = 0; i < 8; i++) {
        float v = (float)sp[i];
        unsigned short hi = f2b(v);
        rh[i] = (short)hi;
        rl[i] = (short)f2b(v - b2f(hi));
    }
    *(bf16x8*)dh = rh;
    *(bf16x8*)dl = rl;
}

// ---------------------------------------------------------------- dtype detect
__global__ void detect_dtype(const unsigned int* __restrict__ x, int* __restrict__ flag) {
    __shared__ int cnt;
    if (threadIdx.x == 0) cnt = 0;
    __syncthreads();
    int bad = 0;
    for (int i = threadIdx.x; i < 4096; i += 256) {
        unsigned short lo = (unsigned short)(x[i] & 0xFFFFu);
        int e = (lo >> 7) & 0xFF;
        if (e != 0 && (e < 0x60 || e > 0x9F)) bad++;
    }
    atomicAdd(&cnt, bad);
    __syncthreads();
    if (threadIdx.x == 0) flag[0] = (cnt > 100) ? 1 : 0;
}

// ---------------------------------------------------------------- weights transpose -> bf16 hi + lo
__global__ void transpose_weights(const void* __restrict__ Wqkv, const void* __restrict__ WEl,
                                  const void* __restrict__ WOl, const void* __restrict__ WOel,
                                  const void* __restrict__ fW1, const void* __restrict__ fW2,
                                  const void* __restrict__ feW1, const void* __restrict__ feW2,
                                  unsigned short* __restrict__ wT,
                                  unsigned short* __restrict__ wTlo,
                                  const int* __restrict__ flag) {
    int f = flag[0];
    int m = blockIdx.x >> 6, part = blockIdx.x & 63;
    int l = m / 10, j = m % 10;
    const void* base; long eoff;
    switch (j) {
        case 0: case 1: case 2: base = Wqkv; eoff = (long)(l * 3 + j) * 16384; break;
        case 3: base = WEl;  eoff = (long)l * 16384; break;
        case 4: base = WOl;  eoff = (long)l * 16384; break;
        case 5: base = WOel; eoff = (long)l * 16384; break;
        case 6: base = fW1;  eoff = (long)l * 16384; break;
        case 7: base = fW2;  eoff = (long)l * 16384; break;
        case 8: base = feW1; eoff = (long)l * 16384; break;
        default: base = feW2; eoff = (long)l * 16384; break;
    }
    int o = part * 256 + threadIdx.x;   // o = n*128 + k
    int n = o >> 7, k = o & 127;
    float w = ldin(base, eoff + k * 128 + n, f);
    unsigned short hi = f2b(w);
    wT[(size_t)m * 16384 + o] = hi;
    wTlo[(size_t)m * 16384 + o] = f2b(w - b2f(hi));
}

// ---------------------------------------------------------------- CSR build
__global__ void zero_int(int* __restrict__ p, int n) {
    int i = blockIdx.x * 256 + threadIdx.x;
    if (i < n) p[i] = 0;
}
__global__ void zero_f32(float* __restrict__ p, int n) {
    int i = blockIdx.x * 256 + threadIdx.x;
    if (i < n) p[i] = 0.f;
}
__global__ void hist_kernel(const int* __restrict__ dst, int* __restrict__ deg, int E) {
    int i = blockIdx.x * 256 + threadIdx.x;
    if (i < E) atomicAdd(&deg[dst[i]], 1);
}
__global__ __launch_bounds__(1024) void scan_kernel(int* __restrict__ deg,
                                                    int* __restrict__ indptr, int N, int E) {
    __shared__ int tmp[1024];
    int t = threadIdx.x;
    int CH = (N + 1023) / 1024;
    int i0 = t * CH;
    int s = 0;
    for (int j = 0; j < CH; j++) { int idx = i0 + j; if (idx < N) s += deg[idx]; }
    tmp[t] = s; __syncthreads();
    for (int off = 1; off < 1024; off <<= 1) {
        int v = (t >= off) ? tmp[t - off] : 0;
        __syncthreads();
        tmp[t] += v;
        __syncthreads();
    }
    int run = (t == 0) ? 0 : tmp[t - 1];
    for (int j = 0; j < CH; j++) {
        int idx = i0 + j;
        if (idx < N) { int dv = deg[idx]; indptr[idx] = run; deg[idx] = run; run += dv; }
    }
    if (t == 0) indptr[N] = E;
}
__global__ void fill_kernel(const int* __restrict__ src, const int* __restrict__ dst,
                            int* __restrict__ cursor, int* __restrict__ pos,
                            unsigned short* __restrict__ srcCSR, int E) {
    int i = blockIdx.x * 256 + threadIdx.x;
    if (i < E) {
        int p = atomicAdd(&cursor[dst[i]], 1);
        pos[i] = p;
        srcCSR[p] = (unsigned short)src[i];
    }
}

// ---------------------------------------------------------------- init h (fp16) / e (fp16)
__global__ __launch_bounds__(256) void init_h(const void* __restrict__ x, const void* __restrict__ pe,
                                              const void* __restrict__ Wn, const void* __restrict__ Wpe,
                                              _Float16* __restrict__ h, const int* __restrict__ flag, int N) {
    __shared__ float WnS[64 * 128];
    __shared__ float WpeS[16 * 128];
    __shared__ float xr[2][64];
    __shared__ float per[2][16];
    int f = flag[0]; int t = threadIdx.x;
    for (int i = t; i < 8192; i += 256) WnS[i] = ldin(Wn, i, f);
    for (int i = t; i < 2048; i += 256) WpeS[i] = ldin(Wpe, i, f);
    long r0 = (long)blockIdx.x * 2;
    if (t < 128) { int rr = t >> 6, k = t & 63; long rg = r0 + rr; if (rg < N) xr[rr][k] = ldin(x, rg * 64 + k, f); }
    else if (t < 160) { int q = t - 128; int rr = q >> 4, k = q & 15; long rg = r0 + rr; if (rg < N) per[rr][k] = ldin(pe, rg * 16 + k, f); }
    __syncthreads();
    int half = t >> 7, c = t & 127;
    long r = r0 + half;
    if (r >= N) return;
    float acc = 0.f;
#pragma unroll 8
    for (int k = 0; k < 64; k++) acc += xr[half][k] * WnS[k * 128 + c];
#pragma unroll
    for (int k = 0; k < 16; k++) acc += per[half][k] * WpeS[k * 128 + c];
    h[r * 128 + c] = (_Float16)acc;
}
__global__ __launch_bounds__(256) void init_e(const void* __restrict__ ea, const void* __restrict__ We,
                                              _Float16* __restrict__ e, const int* __restrict__ flag, int E) {
    __shared__ float WeT[128 * 17];
    __shared__ float rows[16][16];
    int f = flag[0]; int t = threadIdx.x;
    for (int i = t; i < 2048; i += 256) {
        int k = i >> 7, c = i & 127;
        WeT[c * 17 + k] = ldin(We, i, f);
    }
    long r0 = (long)blockIdx.x * 16;
    { int rr = t >> 4, k = t & 15; rows[rr][k] = ldin(ea, (r0 + rr) * 16 + k, f); }
    __syncthreads();
#pragma unroll
    for (int p = 0; p < 8; p++) {
        int idx = t + p * 256;
        int rr = idx >> 7, c = idx & 127;
        float acc = 0.f;
#pragma unroll
        for (int k = 0; k < 16; k++) acc += rows[rr][k] * WeT[c * 17 + k];
        e[(r0 + rr) * 128 + c] = (_Float16)acc;
    }
}

// ---------------------------------------------------------------- node GEMM (split precision)
template <bool RELU, bool RES>
__global__ __launch_bounds__(256, 2) void gemm_node(const _Float16* __restrict__ A,
                                                    const unsigned short* __restrict__ Wt,
                                                    const unsigned short* __restrict__ Wtlo,
                                                    const void* __restrict__ bias, long boff,
                                                    const _Float16* __restrict__ Rp,
                                                    _Float16* __restrict__ C, int M,
                                                    const int* __restrict__ flag) {
    __shared__ unsigned short Ah[128 * 136];
    __shared__ unsigned short Al[128 * 136];
    int t = threadIdx.x;
    long bRow = (long)blockIdx.x * 128;
    {
        int r = t >> 1, ch = (t & 1) * 64;
        long gr = bRow + r;
        unsigned short* dh = &Ah[r * 136 + ch];
        unsigned short* dl = &Al[r * 136 + ch];
        if (gr < M) {
            const _Float16* sp = A + gr * 128 + ch;
#pragma unroll
            for (int i = 0; i < 8; i++) stage8_split(dh + i * 8, dl + i * 8, sp + i * 8);
        } else {
            int4 z = make_int4(0, 0, 0, 0);
#pragma unroll
            for (int i = 0; i < 8; i++) { *(int4*)(dh + i * 8) = z; *(int4*)(dl + i * 8) = z; }
        }
    }
    __syncthreads();
    int wave = t >> 6, lane = t & 63;
    int wr = (wave >> 1) * 64, wc = (wave & 1) * 64;
    int lm = lane & 15, lq = lane >> 4;
    f32x4 acc[4][4];
#pragma unroll
    for (int i = 0; i < 4; i++)
#pragma unroll
        for (int j = 0; j < 4; j++) acc[i][j] = (f32x4){0.f, 0.f, 0.f, 0.f};
#pragma unroll
    for (int ks = 0; ks < 4; ks++) {
        int ko = ks * 32 + lq * 8;
        bf16x8 bh[4], bl[4], ah[4], al[4];
#pragma unroll
        for (int j = 0; j < 4; j++) {
            bh[j] = *(const bf16x8*)(Wt + (wc + j * 16 + lm) * 128 + ko);
            bl[j] = *(const bf16x8*)(Wtlo + (wc + j * 16 + lm) * 128 + ko);
        }
#pragma unroll
        for (int i = 0; i < 4; i++) {
            ah[i] = *(const bf16x8*)&Ah[(wr + i * 16 + lm) * 136 + ko];
            al[i] = *(const bf16x8*)&Al[(wr + i * 16 + lm) * 136 + ko];
        }
#pragma unroll
        for (int i = 0; i < 4; i++)
#pragma unroll
            for (int j = 0; j < 4; j++) {
                acc[i][j] = __builtin_amdgcn_mfma_f32_16x16x32_bf16(ah[i], bh[j], acc[i][j], 0, 0, 0);
                acc[i][j] = __builtin_amdgcn_mfma_f32_16x16x32_bf16(al[i], bh[j], acc[i][j], 0, 0, 0);
                acc[i][j] = __builtin_amdgcn_mfma_f32_16x16x32_bf16(ah[i], bl[j], acc[i][j], 0, 0, 0);
            }
    }
    int f = flag[0];
#pragma unroll
    for (int j = 0; j < 4; j++) {
        int col = wc + j * 16 + lm;
        float bv = ldin(bias, boff + col, f);
#pragma unroll
        for (int i = 0; i < 4; i++) {
#pragma unroll
            for (int r4 = 0; r4 < 4; r4++) {
                long grow = bRow + wr + i * 16 + lq * 4 + r4;
                if (grow < M) {
                    float v = acc[i][j][r4] + bv;
                    if (RES) v += (float)Rp[grow * 128 + col];
                    if (RELU) v = v > 0.f ? v : 0.f;
                    C[grow * 128 + col] = (_Float16)v;
                }
            }
        }
    }
}

// ---------------------------------------------------------------- Q,K GEMMs (h staged once, split precision)
__global__ __launch_bounds__(256, 2) void node_qk(const _Float16* __restrict__ h,
                                                  const unsigned short* __restrict__ wq,
                                                  const unsigned short* __restrict__ wqlo,
                                                  const unsigned short* __restrict__ wk,
                                                  const unsigned short* __restrict__ wklo,
                                                  const void* __restrict__ bqkv, long boff0,
                                                  _Float16* __restrict__ Qb,
                                                  _Float16* __restrict__ Kb,
                                                  const int* __restrict__ flag, int M) {
    __shared__ unsigned short Ah[128 * 136];
    __shared__ unsigned short Al[128 * 136];
    int t = threadIdx.x;
    long bRow = (long)blockIdx.x * 128;
    {
        int r = t >> 1, ch = (t & 1) * 64;
        long gr = bRow + r;
        unsigned short* dh = &Ah[r * 136 + ch];
        unsigned short* dl = &Al[r * 136 + ch];
        if (gr < M) {
            const _Float16* sp = h + gr * 128 + ch;
#pragma unroll
            for (int i = 0; i < 8; i++) stage8_split(dh + i * 8, dl + i * 8, sp + i * 8);
        } else {
            int4 z = make_int4(0, 0, 0, 0);
#pragma unroll
            for (int i = 0; i < 8; i++) { *(int4*)(dh + i * 8) = z; *(int4*)(dl + i * 8) = z; }
        }
    }
    __syncthreads();
    int wave = t >> 6, lane = t & 63;
    int wr = (wave >> 1) * 64, wc = (wave & 1) * 64;
    int lm = lane & 15, lq = lane >> 4;
    int f = flag[0];
    _Float16* outs[2] = {Qb, Kb};
    const unsigned short* whi[2] = {wq, wk};
    const unsigned short* wlo[2] = {wqlo, wklo};
    for (int w = 0; w < 2; w++) {
        f32x4 acc[4][4];
#pragma unroll
        for (int i = 0; i < 4; i++)
#pragma unroll
            for (int j = 0; j < 4; j++) acc[i][j] = (f32x4){0.f, 0.f, 0.f, 0.f};
#pragma unroll
        for (int ks = 0; ks < 4; ks++) {
            int ko = ks * 32 + lq * 8;
            bf16x8 bh[4], bl[4], ah[4], al[4];
#pragma unroll
            for (int j = 0; j < 4; j++) {
                bh[j] = *(const bf16x8*)(whi[w] + (wc + j * 16 + lm) * 128 + ko);
                bl[j] = *(const bf16x8*)(wlo[w] + (wc + j * 16 + lm) * 128 + ko);
            }
#pragma unroll
            for (int i = 0; i < 4; i++) {
                ah[i] = *(const bf16x8*)&Ah[(wr + i * 16 + lm) * 136 + ko];
                al[i] = *(const bf16x8*)&Al[(wr + i * 16 + lm) * 136 + ko];
            }
#pragma unroll
            for (int i = 0; i < 4; i++)
#pragma unroll
                for (int j = 0; j < 4; j++) {
                    acc[i][j] = __builtin_amdgcn_mfma_f32_16x16x32_bf16(ah[i], bh[j], acc[i][j], 0, 0, 0);
                    acc[i][j] = __builtin_amdgcn_mfma_f32_16x16x32_bf16(al[i], bh[j], acc[i][j], 0, 0, 0);
                    acc[i][j] = __builtin_amdgcn_mfma_f32_16x16x32_bf16(ah[i], bl[j], acc[i][j], 0, 0, 0);
                }
        }
        _Float16* O = outs[w];
#pragma unroll
        for (int j = 0; j < 4; j++) {
            int col = wc + j * 16 + lm;
            float bv = ldin(bqkv, boff0 + w * 128 + col, f);
#pragma unroll
            for (int i = 0; i < 4; i++)
#pragma unroll
                for (int r4 = 0; r4 < 4; r4++) {
                    long grow = bRow + wr + i * 16 + lq * 4 + r4;
                    if (grow < M) O[grow * 128 + col] = (_Float16)(acc[i][j][r4] + bv);
                }
        }
    }
}

// ---------------------------------------------------------------- fused edge attention (BN-folded input)
// input e_norm = ebuf*nS+nH (nS null -> identity); writeE=0: scores only (layer 3)
template <typename TS>
__global__ __launch_bounds__(256, 3) void edge_fused0(_Float16* __restrict__ ebuf,
                                                      const unsigned short* __restrict__ W1t,
                                                      const unsigned short* __restrict__ W2t,
                                                      const void* __restrict__ bias1, long b1off,
                                                      const void* __restrict__ bias2, long b2off,
                                                      const _Float16* __restrict__ Qb,
                                                      const _Float16* __restrict__ Kb,
                                                      const int* __restrict__ srcp,
                                                      const int* __restrict__ dstp,
                                                      const int* __restrict__ posp,
                                                      TS* __restrict__ score,
                                                      const int* __restrict__ flag,
                                                      const float* __restrict__ nS,
                                                      const float* __restrict__ nH,
                                                      int writeE) {
    __shared__ unsigned short Es[128 * 136];
    __shared__ int sdst[128], ssrc[128], spos[128];
    __shared__ float nSs[128], nHs[128];
    int t = threadIdx.x;
    long bRow = (long)blockIdx.x * 128;   // E % 128 == 0
    if (t < 128) {
        nSs[t] = nS ? nS[t] : 1.f;
        nHs[t] = nH ? nH[t] : 0.f;
        sdst[t] = dstp[bRow + t]; ssrc[t] = srcp[bRow + t]; spos[t] = posp[bRow + t];
    }
    __syncthreads();
    {
        int r = t >> 1, ch = (t & 1) * 64;
        const _Float16* sp = ebuf + (bRow + r) * 128 + ch;
        unsigned short* dl = &Es[r * 136 + ch];
#pragma unroll
        for (int i = 0; i < 8; i++) stage8n(dl + i * 8, sp + i * 8, &nSs[ch + i * 8], &nHs[ch + i * 8]);
    }
    __syncthreads();
    int wave = t >> 6, lane = t & 63;
    int wr = (wave >> 1) * 64, wc = (wave & 1) * 64;
    int lm = lane & 15, lq = lane >> 4;
    int f = flag[0];
    // ---- GEMM1: Eh
    f32x4 acc[4][4];
#pragma unroll
    for (int i = 0; i < 4; i++)
#pragma unroll
        for (int j = 0; j < 4; j++) acc[i][j] = (f32x4){0.f, 0.f, 0.f, 0.f};
    {
        bf16x8 bfr[4][4];
#pragma unroll
        for (int ks = 0; ks < 4; ks++)
#pragma unroll
            for (int j = 0; j < 4; j++)
                bfr[ks][j] = *(const bf16x8*)(W1t + (wc + j * 16 + lm) * 128 + ks * 32 + lq * 8);
#pragma unroll
        for (int ks = 0; ks < 4; ks++) {
            int ko = ks * 32 + lq * 8;
            bf16x8 af[4];
#pragma unroll
            for (int i = 0; i < 4; i++) af[i] = *(const bf16x8*)&Es[(wr + i * 16 + lm) * 136 + ko];
#pragma unroll
            for (int i = 0; i < 4; i++)
#pragma unroll
                for (int j = 0; j < 4; j++)
                    acc[i][j] = __builtin_amdgcn_mfma_f32_16x16x32_bf16(af[i], bfr[ks][j], acc[i][j], 0, 0, 0);
        }
    }
    __syncthreads();   // all waves done reading Es (GEMM1)
    // ---- middle: qijk = (Eh+b1) * Q[dst] * K[src] * SCALE
#pragma unroll
    for (int j = 0; j < 4; j++) {
        int col = wc + j * 16 + lm;
        float bv = ldin(bias1, b1off + col, f);
#pragma unroll
        for (int i = 0; i < 4; i++) {
#pragma unroll
            for (int r4 = 0; r4 < 4; r4++) {
                int rl = wr + i * 16 + lq * 4 + r4;
                float eh = acc[i][j][r4] + bv;
                float qv = (float)Qb[(long)sdst[rl] * 128 + col];
                float kv = (float)Kb[(long)ssrc[rl] * 128 + col];
                acc[i][j][r4] = eh * qv * kv * 0.25f;
            }
        }
    }
    // ---- score: reduce 16-col head segments; scatter to CSR slot
#pragma unroll
    for (int i = 0; i < 4; i++)
#pragma unroll
        for (int j = 0; j < 4; j++)
#pragma unroll
            for (int r4 = 0; r4 < 4; r4++) {
                float s = acc[i][j][r4];
                s += __shfl_xor(s, 1); s += __shfl_xor(s, 2);
                s += __shfl_xor(s, 4); s += __shfl_xor(s, 8);
                if (lm == 0) {
                    int rl = wr + i * 16 + lq * 4 + r4;
                    s = fminf(fmaxf(s, -60000.f), 60000.f);
                    score[(long)spos[rl] * 8 + (wc >> 4) + j] = (TS)s;
                }
            }
    if (!writeE) return;   // layer 3: edge state dead downstream
    // ---- write qijk to Es as A-operand of GEMM2
#pragma unroll
    for (int i = 0; i < 4; i++)
#pragma unroll
        for (int j = 0; j < 4; j++)
#pragma unroll
            for (int r4 = 0; r4 < 4; r4++)
                Es[(wr + i * 16 + lq * 4 + r4) * 136 + wc + j * 16 + lm] = f2b(acc[i][j][r4]);
    __syncthreads();
    // ---- GEMM2: qijk @ WOel + bOel + e_norm  (raw store)
#pragma unroll
    for (int i = 0; i < 4; i++)
#pragma unroll
        for (int j = 0; j < 4; j++) acc[i][j] = (f32x4){0.f, 0.f, 0.f, 0.f};
    {
        bf16x8 bfr[4][4];
#pragma unroll
        for (int ks = 0; ks < 4; ks++)
#pragma unroll
            for (int j = 0; j < 4; j++)
                bfr[ks][j] = *(const bf16x8*)(W2t + (wc + j * 16 + lm) * 128 + ks * 32 + lq * 8);
#pragma unroll
        for (int ks = 0; ks < 4; ks++) {
            int ko = ks * 32 + lq * 8;
            bf16x8 af[4];
#pragma unroll
            for (int i = 0; i < 4; i++) af[i] = *(const bf16x8*)&Es[(wr + i * 16 + lm) * 136 + ko];
#pragma unroll
            for (int i = 0; i < 4; i++)
#pragma unroll
                for (int j = 0; j < 4; j++)
                    acc[i][j] = __builtin_amdgcn_mfma_f32_16x16x32_bf16(af[i], bfr[ks][j], acc[i][j], 0, 0, 0);
        }
    }
#pragma unroll
    for (int j = 0; j < 4; j++) {
        int col = wc + j * 16 + lm;
        float bo = ldin(bias2, b2off + col, f);
        float sc = nSs[col], sh = nHs[col];
#pragma unroll
        for (int i = 0; i < 4; i++)
#pragma unroll
            for (int r4 = 0; r4 < 4; r4++) {
                long ge = bRow + wr + i * 16 + lq * 4 + r4;
                float en = (float)ebuf[ge * 128 + col] * sc + sh;
                ebuf[ge * 128 + col] = (_Float16)(acc[i][j][r4] + bo + en);
            }
    }
}

// ---------------------------------------------------------------- edge FFN (BN-folded input, in-place)
__global__ __launch_bounds__(256, 3) void edge_ffn(_Float16* __restrict__ ebuf,
                                                   const unsigned short* __restrict__ W1t,
                                                   const unsigned short* __restrict__ W2t,
                                                   const void* __restrict__ bias1, long b1off,
                                                   const void* __restrict__ bias2, long b2off,
                                                   const int* __restrict__ flag,
                                                   const float* __restrict__ nS,
                                                   const float* __restrict__ nH) {
    __shared__ unsigned short Es[128 * 136];
    __shared__ float nSs[128], nHs[128];
    int t = threadIdx.x;
    long bRow = (long)blockIdx.x * 128;
    if (t < 128) { nSs[t] = nS[t]; nHs[t] = nH[t]; }
    __syncthreads();
    {
        int r = t >> 1, ch = (t & 1) * 64;
        const _Float16* sp = ebuf + (bRow + r) * 128 + ch;
        unsigned short* dl = &Es[r * 136 + ch];
#pragma unroll
        for (int i = 0; i < 8; i++) stage8n(dl + i * 8, sp + i * 8, &nSs[ch + i * 8], &nHs[ch + i * 8]);
    }
    __syncthreads();
    int wave = t >> 6, lane = t & 63;
    int wr = (wave >> 1) * 64, wc = (wave & 1) * 64;
    int lm = lane & 15, lq = lane >> 4;
    int f = flag[0];
    f32x4 acc[4][4];
#pragma unroll
    for (int i = 0; i < 4; i++)
#pragma unroll
        for (int j = 0; j < 4; j++) acc[i][j] = (f32x4){0.f, 0.f, 0.f, 0.f};
#pragma unroll
    for (int ks = 0; ks < 4; ks++) {
        int ko = ks * 32 + lq * 8;
        bf16x8 bfr[4], af[4];
#pragma unroll
        for (int j = 0; j < 4; j++) bfr[j] = *(const bf16x8*)(W1t + (wc + j * 16 + lm) * 128 + ko);
#pragma unroll
        for (int i = 0; i < 4; i++) af[i] = *(const bf16x8*)&Es[(wr + i * 16 + lm) * 136 + ko];
#pragma unroll
        for (int i = 0; i < 4; i++)
#pragma unroll
            for (int j = 0; j < 4; j++)
                acc[i][j] = __builtin_amdgcn_mfma_f32_16x16x32_bf16(af[i], bfr[j], acc[i][j], 0, 0, 0);
    }
    __syncthreads();
#pragma unroll
    for (int j = 0; j < 4; j++) {
        int col = wc + j * 16 + lm;
        float bv = ldin(bias1, b1off + col, f);
#pragma unroll
        for (int i = 0; i < 4; i++)
#pragma unroll
            for (int r4 = 0; r4 < 4; r4++) {
                float v = acc[i][j][r4] + bv;
                v = v > 0.f ? v : 0.f;
                Es[(wr + i * 16 + lq * 4 + r4) * 136 + col] = f2b(v);
            }
    }
    __syncthreads();
#pragma unroll
    for (int i = 0; i < 4; i++)
#pragma unroll
        for (int j = 0; j < 4; j++) acc[i][j] = (f32x4){0.f, 0.f, 0.f, 0.f};
#pragma unroll
    for (int ks = 0; ks < 4; ks++) {
        int ko = ks * 32 + lq * 8;
        bf16x8 bfr[4], af[4];
#pragma unroll
        for (int j = 0; j < 4; j++) bfr[j] = *(const bf16x8*)(W2t + (wc + j * 16 + lm) * 128 + ko);
#pragma unroll
        for (int i = 0; i < 4; i++) af[i] = *(const bf16x8*)&Es[(wr + i * 16 + lm) * 136 + ko];
#pragma unroll
        for (int i = 0; i < 4; i++)
#pragma unroll
            for (int j = 0; j < 4; j++)
                acc[i][j] = __builtin_amdgcn_mfma_f32_16x16x32_bf16(af[i], bfr[j], acc[i][j], 0, 0, 0);
    }
#pragma unroll
    for (int j = 0; j < 4; j++) {
        int col = wc + j * 16 + lm;
        float bv = ldin(bias2, b2off + col, f);
        float sc = nSs[col], sh = nHs[col];
#pragma unroll
        for (int i = 0; i < 4; i++)
#pragma unroll
            for (int r4 = 0; r4 < 4; r4++) {
                long ge = bRow + wr + i * 16 + lq * 4 + r4;
                float en = (float)ebuf[ge * 128 + col] * sc + sh;
                ebuf[ge * 128 + col] = (_Float16)(acc[i][j][r4] + bv + en);
            }
    }
}

// ---------------------------------------------------------------- softmax+agg (CSR-contiguous)
template <typename TS>
__global__ __launch_bounds__(256) void agg_kernel(const int* __restrict__ indptr,
                                                  const unsigned short* __restrict__ srcCSR,
                                                  const TS* __restrict__ score,
                                                  const _Float16* __restrict__ V,
                                                  _Float16* __restrict__ agg, int N) {
    int wave = threadIdx.x >> 6, lane = threadIdx.x & 63;
    int n = blockIdx.x * 4 + wave;
    if (n >= N) return;
    int beg = indptr[n], end = indptr[n + 1];
    int h0 = lane >> 4, h1 = 4 + h0;
    float m0 = -3.402823466e38f, m1 = -3.402823466e38f;
    for (int i = beg; i < end; i++) {
        m0 = fmaxf(m0, (float)score[(long)i * 8 + h0]);
        m1 = fmaxf(m1, (float)score[(long)i * 8 + h1]);
    }
    float a0 = 0.f, a1 = 0.f, d0 = 0.f, d1 = 0.f;
    for (int i = beg; i < end; i++) {
        int sv = srcCSR[i];
        float p0 = __expf((float)score[(long)i * 8 + h0] - m0);
        float p1 = __expf((float)score[(long)i * 8 + h1] - m1);
        d0 += p0; d1 += p1;
        a0 += p0 * (float)V[(long)sv * 128 + lane];
        a1 += p1 * (float)V[(long)sv * 128 + 64 + lane];
    }
    float inv0 = 1.f / (d0 + 1e-16f), inv1 = 1.f / (d1 + 1e-16f);
    agg[(long)n * 128 + lane] = (_Float16)(a0 * inv0);
    agg[(long)n * 128 + 64 + lane] = (_Float16)(a1 * inv1);
}

// ---------------------------------------------------------------- BatchNorm
__global__ __launch_bounds__(256) void bn_stats(const _Float16* __restrict__ y, float* __restrict__ sums, int M) {
    __shared__ float lsum[16 * 128];
    __shared__ float lss[16 * 128];
    int t = threadIdx.x;
    int chb = (t & 15) * 8;
    int rowlane = t >> 4;
    float s[8], ss[8];
#pragma unroll
    for (int k = 0; k < 8; k++) { s[k] = 0.f; ss[k] = 0.f; }
    for (long r = (long)blockIdx.x * 16 + rowlane; r < M; r += (long)gridDim.x * 16) {
        int4 raw = *(const int4*)(y + r * 128 + chb);
        const _Float16* a = (const _Float16*)&raw;
#pragma unroll
        for (int k = 0; k < 8; k++) {
            float v = (float)a[k];
            s[k] += v; ss[k] += v * v;
        }
    }
#pragma unroll
    for (int k = 0; k < 8; k++) {
        lsum[rowlane * 128 + chb + k] = s[k];
        lss[rowlane * 128 + chb + k] = ss[k];
    }
    __syncthreads();
    if (t < 128) {
        float t1 = 0.f, t2 = 0.f;
#pragma unroll
        for (int row = 0; row < 16; row++) {
            t1 += lsum[row * 128 + t];
            t2 += lss[row * 128 + t];
        }
        atomicAdd(&sums[t], t1);
        atomicAdd(&sums[128 + t], t2);
    }
}
__global__ void bn_finalize(const float* __restrict__ sums,
                            const void* __restrict__ gamma, long goff,
                            const void* __restrict__ beta, long boff,
                            float* __restrict__ scale, float* __restrict__ shift,
                            float invM, const int* __restrict__ flag) {
    int f = flag[0];
    int c = threadIdx.x;
    float mu = sums[c] * invM;
    float var = fmaxf(sums[128 + c] * invM - mu * mu, 0.f);
    float rs = rsqrtf(var + 1e-5f);
    float g = ldin(gamma, goff + c, f) * rs;
    scale[c] = g;
    shift[c] = ldin(beta, boff + c, f) - mu * g;
}
__global__ void bn_apply(_Float16* __restrict__ y, const float* __restrict__ scale,
                         const float* __restrict__ shift, long total) {
    long idx = ((long)blockIdx.x * 256 + threadIdx.x) * 8;
    long stride = (long)gridDim.x * 256 * 8;
    for (; idx < total; idx += stride) {
        int cb = (int)(idx & 127);
        _Float16* p = y + idx;
        int4 v = *(int4*)p;
        _Float16* a = (_Float16*)&v;
        _Float16 o[8];
#pragma unroll
        for (int k = 0; k < 8; k++) o[k] = (_Float16)((float)a[k] * scale[cb + k] + shift[cb + k]);
        *(int4*)p = *(int4*)o;
    }
}

// ---------------------------------------------------------------- pool + heads
__global__ __launch_bounds__(128) void pool_kernel(const _Float16* __restrict__ h,
                                                   const int* __restrict__ batch,
                                                   float* __restrict__ g, int N) {
    int gid = blockIdx.x;
    int lo = 0, hi = N;
    while (lo < hi) { int mid = (lo + hi) >> 1; if (batch[mid] < gid) lo = mid + 1; else hi = mid; }
    int beg = lo;
    hi = N;
    while (lo < hi) { int mid = (lo + hi) >> 1; if (batch[mid] < gid + 1) lo = mid + 1; else hi = mid; }
    int end = lo;
    int c = threadIdx.x;
    float acc = 0.f;
    for (int r = beg; r < end; r++) acc += (float)h[(long)r * 128 + c];
    g[gid * 128 + c] = acc;
}
__global__ __launch_bounds__(128) void head_kernel(const float* __restrict__ g,
                                                   const void* muW1, const void* mub1,
                                                   const void* muW2, const void* mub2,
                                                   const void* lvW1, const void* lvb1,
                                                   const void* lvW2, const void* lvb2,
                                                   void* __restrict__ out, const int* __restrict__ flag) {
    __shared__ float gr[128];
    __shared__ float red[128];
    int f = flag[0];
    int r = blockIdx.x, t = threadIdx.x;
    gr[t] = g[r * 128 + t];
    __syncthreads();
    float acc = ldin(mub1, t, f);
    for (int k = 0; k < 128; k++) acc += gr[k] * ldin(muW1, k * 128 + t, f);
    acc = fmaxf(acc, 0.f);
    red[t] = acc * ldin(muW2, t, f);
    __syncthreads();
    for (int s = 64; s > 0; s >>= 1) { if (t < s) red[t] += red[t + s]; __syncthreads(); }
    if (t == 0) {
        float v = red[0] + ldin(mub2, 0, f);
        if (f) ((float*)out)[r] = v; else ((unsigned short*)out)[r] = f2b(v);
    }
    __syncthreads();
    acc = ldin(lvb1, t, f);
    for (int k = 0; k < 128; k++) acc += gr[k] * ldin(lvW1, k * 128 + t, f);
    acc = fmaxf(acc, 0.f);
    red[t] = acc * ldin(lvW2, t, f);
    __syncthreads();
    for (int s = 64; s > 0; s >>= 1) { if (t < s) red[t] += red[t + s]; __syncthreads(); }
    if (t == 0) {
        float v = __expf(0.5f * (red[0] + ldin(lvb2, 0, f)));
        if (f) ((float*)out)[128 + r] = v; else ((unsigned short*)out)[128 + r] = f2b(v);
    }
}

// ---------------------------------------------------------------- host
extern "C" void kernel_launch(void* const* d_in, const int* in_sizes, int n_in,
                              void* d_out, int out_size, void* d_ws, size_t ws_size,
                              hipStream_t stream) {
    const void* x    = d_in[0];
    const void* ea   = d_in[1];
    const void* pe   = d_in[2];
    const int* eidx  = (const int*)d_in[3];
    const int* batch = (const int*)d_in[4];
    const int* srcp = eidx;
    const int* dstp = eidx + E_EDGES;

    bool score_f32 = (ws_size >= 148000000ULL);
    size_t ts_size = score_f32 ? 4 : 2;

    char* wsb = (char*)d_ws;
    size_t off = 0;
    auto alloc = [&](size_t bytes) -> char* {
        char* p = wsb + off;
        off = (off + bytes + 255) & ~(size_t)255;
        return p;
    };
    int* dflag            = (int*)alloc(256);
    unsigned short* wT    = (unsigned short*)alloc(40UL * 16384 * 2);
    unsigned short* wTlo  = (unsigned short*)alloc(40UL * 16384 * 2);
    _Float16* ebuf        = (_Float16*)alloc((size_t)E_EDGES * 128 * 2);
    _Float16* hbuf        = (_Float16*)alloc((size_t)N_NODES * 128 * 2);
    char* slotA           = alloc((size_t)N_NODES * 128 * 2);
    char* slotB           = alloc((size_t)N_NODES * 128 * 2);
    char* scoreB          = alloc((size_t)E_EDGES * 8 * ts_size);
    int* indptr           = (int*)alloc((size_t)(N_NODES + 1) * 4);
    int* deg              = (int*)alloc((size_t)N_NODES * 4);
    int* pos              = (int*)alloc((size_t)E_EDGES * 4);
    unsigned short* srcCSR= (unsigned short*)alloc((size_t)E_EDGES * 2);
    float* sums           = (float*)alloc(256 * 4);
    float* scalArr        = (float*)alloc(16 * 128 * 4);
    float* shftArr        = (float*)alloc(16 * 128 * 4);
    float* gpool          = (float*)scoreB;

    _Float16* Qb = (_Float16*)slotA;
    _Float16* Kb = (_Float16*)slotB;
    _Float16* Vb = (_Float16*)slotA;
    _Float16* aggb = (_Float16*)slotB;
    _Float16* hid  = (_Float16*)slotA;

    detect_dtype<<<1, 256, 0, stream>>>((const unsigned int*)x, dflag);
    transpose_weights<<<2560, 256, 0, stream>>>(d_in[8], d_in[10], d_in[12], d_in[14],
                                                d_in[16], d_in[18], d_in[20], d_in[22], wT, wTlo, dflag);
    zero_int<<<(N_NODES + 255) / 256, 256, 0, stream>>>(deg, N_NODES);
    hist_kernel<<<(E_EDGES + 255) / 256, 256, 0, stream>>>(dstp, deg, E_EDGES);
    scan_kernel<<<1, 1024, 0, stream>>>(deg, indptr, N_NODES, E_EDGES);
    fill_kernel<<<(E_EDGES + 255) / 256, 256, 0, stream>>>(srcp, dstp, deg, pos, srcCSR, E_EDGES);
    init_h<<<(N_NODES + 1) / 2, 256, 0, stream>>>(x, pe, d_in[5], d_in[7], hbuf, dflag, N_NODES);
    init_e<<<E_EDGES / 16, 256, 0, stream>>>(ea, d_in[6], ebuf, dflag, E_EDGES);

    const int gN = (N_NODES + 127) / 128;
    const int gE = E_EDGES / 128;

    auto bn_sf = [&](_Float16* y, int M, int s) {
        zero_f32<<<1, 256, 0, stream>>>(sums, 256);
        int sb = (M + 15) / 16; if (sb > 1024) sb = 1024;
        bn_stats<<<sb, 256, 0, stream>>>(y, sums, M);
        bn_finalize<<<1, 128, 0, stream>>>(sums, d_in[24], (long)s * 128, d_in[25], (long)s * 128,
                                           scalArr + s * 128, shftArr + s * 128, 1.f / (float)M, dflag);
    };
    auto bn_full = [&](_Float16* y, int M, int s) {
        bn_sf(y, M, s);
        long total = (long)M * 128;
        int grid = (int)((total / 8 + 255) / 256); if (grid > 4096) grid = 4096;
        bn_apply<<<grid, 256, 0, stream>>>(y, scalArr + s * 128, shftArr + s * 128, total);
    };

    for (int l = 0; l < 4; l++) {
        const unsigned short* WTl = wT + (size_t)l * 10 * 16384;
        const unsigned short* WTlol = wTlo + (size_t)l * 10 * 16384;
        int writeE = (l < 3) ? 1 : 0;
        const float* eS = (l > 0) ? scalArr + ((l - 1) * 4 + 3) * 128 : nullptr;
        const float* eH = (l > 0) ? shftArr + ((l - 1) * 4 + 3) * 128 : nullptr;

        node_qk<<<gN, 256, 0, stream>>>(hbuf, WTl + 0 * 16384, WTlol + 0 * 16384,
                                        WTl + 1 * 16384, WTlol + 1 * 16384,
                                        d_in[9], (long)(l * 3) * 128, Qb, Kb, dflag, N_NODES);
        if (score_f32)
            edge_fused0<float><<<gE, 256, 0, stream>>>(ebuf, WTl + 3 * 16384, WTl + 5 * 16384,
                                                       d_in[11], (long)l * 128, d_in[15], (long)l * 128,
                                                       Qb, Kb, srcp, dstp, pos, (float*)scoreB, dflag, eS, eH, writeE);
        else
            edge_fused0<_Float16><<<gE, 256, 0, stream>>>(ebuf, WTl + 3 * 16384, WTl + 5 * 16384,
                                                          d_in[11], (long)l * 128, d_in[15], (long)l * 128,
                                                          Qb, Kb, srcp, dstp, pos, (_Float16*)scoreB, dflag, eS, eH, writeE);
        gemm_node<false, false><<<gN, 256, 0, stream>>>(hbuf, WTl + 2 * 16384, WTlol + 2 * 16384,
                                                        d_in[9], (long)(l * 3 + 2) * 128, nullptr, Vb, N_NODES, dflag);
        if (score_f32)
            agg_kernel<float><<<(N_NODES + 3) / 4, 256, 0, stream>>>(indptr, srcCSR, (const float*)scoreB, Vb, aggb, N_NODES);
        else
            agg_kernel<_Float16><<<(N_NODES + 3) / 4, 256, 0, stream>>>(indptr, srcCSR, (const _Float16*)scoreB, Vb, aggb, N_NODES);
        gemm_node<false, true><<<gN, 256, 0, stream>>>(aggb, WTl + 4 * 16384, WTlol + 4 * 16384,
                                                       d_in[13], (long)l * 128, hbuf, hbuf, N_NODES, dflag);
        bn_full(hbuf, N_NODES, l * 4 + 0);
        gemm_node<true, false><<<gN, 256, 0, stream>>>(hbuf, WTl + 6 * 16384, WTlol + 6 * 16384,
                                                       d_in[17], (long)l * 128, nullptr, hid, N_NODES, dflag);
        gemm_node<false, true><<<gN, 256, 0, stream>>>(hid, WTl + 7 * 16384, WTlol + 7 * 16384,
                                                       d_in[19], (long)l * 128, hbuf, hbuf, N_NODES, dflag);
        bn_full(hbuf, N_NODES, l * 4 + 1);
        if (l < 3) {
            bn_sf(ebuf, E_EDGES, l * 4 + 2);
            edge_ffn<<<gE, 256, 0, stream>>>(ebuf, WTl + 8 * 16384, WTl + 9 * 16384,
                                             d_in[21], (long)l * 128, d_in[23], (long)l * 128, dflag,
                                             scalArr + (l * 4 + 2) * 128, shftArr + (l * 4 + 2) * 128);
            bn_sf(ebuf, E_EDGES, l * 4 + 3);
        }
    }

    pool_kernel<<<G_GRAPHS, 128, 0, stream>>>(hbuf, batch, gpool, N_NODES);
    head_kernel<<<G_GRAPHS, 128, 0, stream>>>(gpool, d_in[26], d_in[27], d_in[28], d_in[29],
                                              d_in[30], d_in[31], d_in[32], d_in[33], d_out, dflag);
}